// Round 1
// 59.789 us; speedup vs baseline: 1.3970x; 1.3970x over previous
//
#include <hip/hip_runtime.h>
#include <stdint.h>

#define NQ 8

// ---------------------------------------------------------------------------
// Algebraic reduction (verified against reference structure):
//   * Every entangling gate acts within a fixed disjoint pair (2p, 2p+1),
//     identically paired across all 3 layers  =>  U = V0 (x) V1 (x) V2 (x) V3,
//     each Vp a 4x4 unitary.
//   * Observable: z = <Z_wire0>, wire 0 is the MSB => Z (x) I on pair 0 only.
//   * Input is a product state phi0 (x) ... (x) phi3, each unit-norm.
//   => z = phi0^T Re(M) phi0,  M = V0^H (Z (x) I2) V0  (4x4 Hermitian),
//      phi0 = [c0c1, c0s1, s0c1, s0s1], ck=cos(x_k/2), sk=sin(x_k/2).
// Pairs 1..3 drop out: <phi_p|Vp^H Vp|phi_p> = 1. The full 256-dim state,
// the MFMA quadratic form and the fp8 A matrix are all unnecessary.
// Sanity: params=0 => V0=CNOT, M=Z(x)I, z=cos(x0) = circuit's exact output.
// ---------------------------------------------------------------------------

// Kernel 1: build Mre = Re(V0^H (Z x I) V0) from pair-0 params (bases 0,16,32).
// One thread; ~10^3 FLOP total. Basis index a = 2*q0 + q1 (q0 = wire0 = MSB).
__global__ __launch_bounds__(64) void build_M(const float* __restrict__ params,
                                              float* __restrict__ M) {
  if (threadIdx.x != 0) return;
  float Vr[4][4], Vi[4][4];
#pragma unroll
  for (int r = 0; r < 4; ++r)
#pragma unroll
    for (int c = 0; c < 4; ++c) {
      Vr[r][c] = (r == c) ? 1.0f : 0.0f;
      Vi[r][c] = 0.0f;
    }

  for (int l = 0; l < 3; ++l) {
    const int base = l * 16;  // layer l, pair 0: params[(l*4 + 0)*4 ...]
    const float p0 = params[base + 0];
    const float p1 = params[base + 1];
    const float p2 = params[base + 2];
    const float p3 = params[base + 3];
    float s, c;

    // RZ(p0) on q0 (bit1 of a): row phase e^{-i p0/2} for q0=0, e^{+i p0/2} for q0=1
    s = sinf(0.5f * p0); c = cosf(0.5f * p0);
#pragma unroll
    for (int r = 0; r < 4; ++r) {
      const float sg = (r & 2) ? s : -s;
#pragma unroll
      for (int cc = 0; cc < 4; ++cc) {
        const float nr = Vr[r][cc] * c - Vi[r][cc] * sg;
        Vi[r][cc] = Vr[r][cc] * sg + Vi[r][cc] * c;
        Vr[r][cc] = nr;
      }
    }
    // RX(p1) on q1 (bit0): newV[r] = c*V[r] - i*s*V[r^1]
    s = sinf(0.5f * p1); c = cosf(0.5f * p1);
    {
      float nr[4][4], ni[4][4];
#pragma unroll
      for (int r = 0; r < 4; ++r)
#pragma unroll
        for (int cc = 0; cc < 4; ++cc) {
          nr[r][cc] = c * Vr[r][cc] + s * Vi[r ^ 1][cc];
          ni[r][cc] = c * Vi[r][cc] - s * Vr[r ^ 1][cc];
        }
#pragma unroll
      for (int r = 0; r < 4; ++r)
#pragma unroll
        for (int cc = 0; cc < 4; ++cc) { Vr[r][cc] = nr[r][cc]; Vi[r][cc] = ni[r][cc]; }
    }
    // CNOT(q0 -> q1): swap rows 2 and 3
#pragma unroll
    for (int cc = 0; cc < 4; ++cc) {
      const float tr = Vr[2][cc], ti = Vi[2][cc];
      Vr[2][cc] = Vr[3][cc]; Vi[2][cc] = Vi[3][cc];
      Vr[3][cc] = tr;        Vi[3][cc] = ti;
    }
    // RZ(p2) on q1
    s = sinf(0.5f * p2); c = cosf(0.5f * p2);
#pragma unroll
    for (int r = 0; r < 4; ++r) {
      const float sg = (r & 1) ? s : -s;
#pragma unroll
      for (int cc = 0; cc < 4; ++cc) {
        const float nr = Vr[r][cc] * c - Vi[r][cc] * sg;
        Vi[r][cc] = Vr[r][cc] * sg + Vi[r][cc] * c;
        Vr[r][cc] = nr;
      }
    }
    // RX(p3) on q1
    s = sinf(0.5f * p3); c = cosf(0.5f * p3);
    {
      float nr[4][4], ni[4][4];
#pragma unroll
      for (int r = 0; r < 4; ++r)
#pragma unroll
        for (int cc = 0; cc < 4; ++cc) {
          nr[r][cc] = c * Vr[r][cc] + s * Vi[r ^ 1][cc];
          ni[r][cc] = c * Vi[r][cc] - s * Vr[r ^ 1][cc];
        }
#pragma unroll
      for (int r = 0; r < 4; ++r)
#pragma unroll
        for (int cc = 0; cc < 4; ++cc) { Vr[r][cc] = nr[r][cc]; Vi[r][cc] = ni[r][cc]; }
    }
  }

  // M[a][b] = sum_m d_m * Re(conj(V[m][a]) * V[m][b]),  d = (+1,+1,-1,-1)
#pragma unroll
  for (int a = 0; a < 4; ++a)
#pragma unroll
    for (int b = 0; b < 4; ++b) {
      float acc = 0.0f;
#pragma unroll
      for (int m = 0; m < 4; ++m) {
        const float d = (m < 2) ? 1.0f : -1.0f;
        acc += d * (Vr[m][a] * Vr[m][b] + Vi[m][a] * Vi[m][b]);
      }
      M[a * 4 + b] = acc;
    }
}

// ---------------------------------------------------------------------------
// Kernel 2: streaming apply. One row per thread: load (x0,x1) as float2,
// z = phi^T M phi, out = sigmoid(z). M loads are wave-uniform (scalar-cached).
// Memory floor: ~4 MB fetch (full 64B lines of the 32B rows) + 0.5 MB write
// ~ 0.72 us @ 6.3 TB/s.
// ---------------------------------------------------------------------------
__global__ __launch_bounds__(256) void qcnn_apply(const float* __restrict__ x,
                                                  const float* __restrict__ M,
                                                  float* __restrict__ out,
                                                  int B) {
  const int i = blockIdx.x * 256 + threadIdx.x;
  if (i >= B) return;

  const float m0  = M[0],  m1  = M[1],  m2  = M[2],  m3  = M[3];
  const float m4  = M[4],  m5  = M[5],  m6  = M[6],  m7  = M[7];
  const float m8  = M[8],  m9  = M[9],  m10 = M[10], m11 = M[11];
  const float m12 = M[12], m13 = M[13], m14 = M[14], m15 = M[15];

  const float2 xv = *reinterpret_cast<const float2*>(x + (size_t)i * NQ);
  float s0, c0, s1, c1;
  __sincosf(0.5f * xv.x, &s0, &c0);
  __sincosf(0.5f * xv.y, &s1, &c1);
  const float p0 = c0 * c1, p1 = c0 * s1, p2 = s0 * c1, p3 = s0 * s1;

  const float y0 = fmaf(m0,  p0, fmaf(m1,  p1, fmaf(m2,  p2, m3  * p3)));
  const float y1 = fmaf(m4,  p0, fmaf(m5,  p1, fmaf(m6,  p2, m7  * p3)));
  const float y2 = fmaf(m8,  p0, fmaf(m9,  p1, fmaf(m10, p2, m11 * p3)));
  const float y3 = fmaf(m12, p0, fmaf(m13, p1, fmaf(m14, p2, m15 * p3)));
  const float z  = fmaf(p0, y0, fmaf(p1, y1, fmaf(p2, y2, p3 * y3)));

  out[i] = 1.0f / (1.0f + __expf(-z));
}

// ---------------------------------------------------------------------------
// ws layout: M[16] f32 (64 B). Everything else from the old pipeline is gone.
// ---------------------------------------------------------------------------
extern "C" void kernel_launch(void* const* d_in, const int* in_sizes, int n_in,
                              void* d_out, int out_size, void* d_ws, size_t ws_size,
                              hipStream_t stream) {
  const float* x = (const float*)d_in[0];
  const float* params = (const float*)d_in[1];
  float* out = (float*)d_out;
  float* M = (float*)d_ws;

  const int B = in_sizes[0] / NQ;  // 131072

  build_M<<<1, 64, 0, stream>>>(params, M);
  qcnn_apply<<<(B + 255) / 256, 256, 0, stream>>>(x, M, out, B);
}

// Round 2
// 57.306 us; speedup vs baseline: 1.4576x; 1.0433x over previous
//
#include <hip/hip_runtime.h>
#include <stdint.h>

#define NQ 8

// ---------------------------------------------------------------------------
// Algebraic reduction (verified in round 1: passed, absmax 3.9e-3):
//   * All entangling gates act within fixed disjoint pairs (2p, 2p+1), same
//     pairing every layer  =>  U = V0 (x) V1 (x) V2 (x) V3 (4x4 unitaries).
//   * Observable Z on wire 0 (MSB) => Z (x) I acts on pair 0 only.
//   * Input is a product state; pairs 1..3 contribute <phi|V^H V|phi> = 1.
//   => z = phi0^T Re(M) phi0,  M = V0^H (Z (x) I2) V0  (4x4),
//      phi0 = [c0c1, c0s1, s0c1, s0s1], ck = cos(x_k/2), sk = sin(x_k/2).
//
// Round-2 change: single fused kernel. M (~600 FLOP + 12 __sincosf) is
// computed redundantly per thread — params loads are wave-uniform (scalar
// unit), the chain overlaps other waves' memory latency, and we drop the
// second launch + inter-kernel bubble + all workspace use.
// ---------------------------------------------------------------------------
__global__ __launch_bounds__(256) void qcnn_fused(const float* __restrict__ x,
                                                  const float* __restrict__ params,
                                                  float* __restrict__ out,
                                                  int B) {
  const int i = blockIdx.x * 256 + threadIdx.x;

  // ---- build V0 = (3 layers of RZ/RX/CNOT/RZ/RX on pair 0), 4x4 complex ----
  float Vr[4][4], Vi[4][4];
#pragma unroll
  for (int r = 0; r < 4; ++r)
#pragma unroll
    for (int c = 0; c < 4; ++c) {
      Vr[r][c] = (r == c) ? 1.0f : 0.0f;
      Vi[r][c] = 0.0f;
    }

#pragma unroll
  for (int l = 0; l < 3; ++l) {
    const int base = l * 16;  // layer l, pair 0: params[(l*4 + 0)*4 ...]
    const float p0 = params[base + 0];
    const float p1 = params[base + 1];
    const float p2 = params[base + 2];
    const float p3 = params[base + 3];
    float s, c;

    // RZ(p0) on q0 (bit1): phase -s for q0=0, +s for q0=1
    __sincosf(0.5f * p0, &s, &c);
#pragma unroll
    for (int r = 0; r < 4; ++r) {
      const float sg = (r & 2) ? s : -s;
#pragma unroll
      for (int cc = 0; cc < 4; ++cc) {
        const float nr = Vr[r][cc] * c - Vi[r][cc] * sg;
        Vi[r][cc] = Vr[r][cc] * sg + Vi[r][cc] * c;
        Vr[r][cc] = nr;
      }
    }
    // RX(p1) on q1 (bit0): newV[r] = c*V[r] - i*s*V[r^1]
    __sincosf(0.5f * p1, &s, &c);
    {
      float nr[4][4], ni[4][4];
#pragma unroll
      for (int r = 0; r < 4; ++r)
#pragma unroll
        for (int cc = 0; cc < 4; ++cc) {
          nr[r][cc] = c * Vr[r][cc] + s * Vi[r ^ 1][cc];
          ni[r][cc] = c * Vi[r][cc] - s * Vr[r ^ 1][cc];
        }
#pragma unroll
      for (int r = 0; r < 4; ++r)
#pragma unroll
        for (int cc = 0; cc < 4; ++cc) { Vr[r][cc] = nr[r][cc]; Vi[r][cc] = ni[r][cc]; }
    }
    // CNOT(q0 -> q1): swap rows 2 and 3
#pragma unroll
    for (int cc = 0; cc < 4; ++cc) {
      const float tr = Vr[2][cc], ti = Vi[2][cc];
      Vr[2][cc] = Vr[3][cc]; Vi[2][cc] = Vi[3][cc];
      Vr[3][cc] = tr;        Vi[3][cc] = ti;
    }
    // RZ(p2) on q1
    __sincosf(0.5f * p2, &s, &c);
#pragma unroll
    for (int r = 0; r < 4; ++r) {
      const float sg = (r & 1) ? s : -s;
#pragma unroll
      for (int cc = 0; cc < 4; ++cc) {
        const float nr = Vr[r][cc] * c - Vi[r][cc] * sg;
        Vi[r][cc] = Vr[r][cc] * sg + Vi[r][cc] * c;
        Vr[r][cc] = nr;
      }
    }
    // RX(p3) on q1
    __sincosf(0.5f * p3, &s, &c);
    {
      float nr[4][4], ni[4][4];
#pragma unroll
      for (int r = 0; r < 4; ++r)
#pragma unroll
        for (int cc = 0; cc < 4; ++cc) {
          nr[r][cc] = c * Vr[r][cc] + s * Vi[r ^ 1][cc];
          ni[r][cc] = c * Vi[r][cc] - s * Vr[r ^ 1][cc];
        }
#pragma unroll
      for (int r = 0; r < 4; ++r)
#pragma unroll
        for (int cc = 0; cc < 4; ++cc) { Vr[r][cc] = nr[r][cc]; Vi[r][cc] = ni[r][cc]; }
    }
  }

  // ---- M[a][b] = sum_m d_m * Re(conj(V[m][a]) * V[m][b]), d=(+,+,-,-) ----
  float M[4][4];
#pragma unroll
  for (int a = 0; a < 4; ++a)
#pragma unroll
    for (int b = 0; b < 4; ++b) {
      float acc = (Vr[0][a] * Vr[0][b] + Vi[0][a] * Vi[0][b]);
      acc += (Vr[1][a] * Vr[1][b] + Vi[1][a] * Vi[1][b]);
      acc -= (Vr[2][a] * Vr[2][b] + Vi[2][a] * Vi[2][b]);
      acc -= (Vr[3][a] * Vr[3][b] + Vi[3][a] * Vi[3][b]);
      M[a][b] = acc;
    }

  // ---- streaming apply: z = phi^T M phi, out = sigmoid(z) ----
  if (i < B) {
    const float2 xv = *reinterpret_cast<const float2*>(x + (size_t)i * NQ);
    float s0, c0, s1, c1;
    __sincosf(0.5f * xv.x, &s0, &c0);
    __sincosf(0.5f * xv.y, &s1, &c1);
    const float p0 = c0 * c1, p1 = c0 * s1, p2 = s0 * c1, p3 = s0 * s1;

    const float y0 = fmaf(M[0][0], p0, fmaf(M[0][1], p1, fmaf(M[0][2], p2, M[0][3] * p3)));
    const float y1 = fmaf(M[1][0], p0, fmaf(M[1][1], p1, fmaf(M[1][2], p2, M[1][3] * p3)));
    const float y2 = fmaf(M[2][0], p0, fmaf(M[2][1], p1, fmaf(M[2][2], p2, M[2][3] * p3)));
    const float y3 = fmaf(M[3][0], p0, fmaf(M[3][1], p1, fmaf(M[3][2], p2, M[3][3] * p3)));
    const float z  = fmaf(p0, y0, fmaf(p1, y1, fmaf(p2, y2, p3 * y3)));

    out[i] = 1.0f / (1.0f + __expf(-z));
  }
}

// ---------------------------------------------------------------------------
// Single launch; no workspace use at all.
// ---------------------------------------------------------------------------
extern "C" void kernel_launch(void* const* d_in, const int* in_sizes, int n_in,
                              void* d_out, int out_size, void* d_ws, size_t ws_size,
                              hipStream_t stream) {
  const float* x = (const float*)d_in[0];
  const float* params = (const float*)d_in[1];
  float* out = (float*)d_out;

  const int B = in_sizes[0] / NQ;  // 131072

  qcnn_fused<<<(B + 255) / 256, 256, 0, stream>>>(x, params, out, B);
}